// Round 20
// baseline (66.010 us; speedup 1.0000x reference)
//
#include <hip/hip_runtime.h>

// RBF Gram via single-pass fp16 MFMA with quantization-cancelling norms.
//   P1: x (fp32 [N][64]) -> H (fp16, XOR-swizzled per 128-row chunk), sq = ||fp16(x)||^2.
//   P2: 64x256 tile per block (A 8KB + B 32KB = 40KB LDS -> 4 blocks/CU).
//       Wave w owns rows w*16..w*16+15 x all 256 cols (acc[16] f32x4).
//       Epilogue: two row-half passes through an 8KB wave-private LDS bounce
//       -> 1 KB contiguous stores, 256 row-streams/CU. R19 bug fixed: the bounce
//       is intra-wave CROSS-LANE LDS communication -> needs compiler fences
//       (memory-clobber + sched_barrier + lgkmcnt) to stop per-thread-disjoint
//       reordering of the write/read passes (HW DS pipe is in-order per wave).

#define GAMMA 0.5f

typedef __attribute__((ext_vector_type(8))) _Float16 half8;
typedef __attribute__((ext_vector_type(4))) float f32x4;

// ---------------- Phase 1: fp16 quantize + swizzle + quantized norms ----------------
__global__ __launch_bounds__(256) void quant_kernel(const float* __restrict__ x,
                                                    unsigned short* __restrict__ H,
                                                    float* __restrict__ sq) {
    int tid = blockIdx.x * 256 + threadIdx.x;   // one float4 (4 elems of one row)
    int row = tid >> 4, c4 = tid & 15;
    float4 v = ((const float4*)x)[tid];
    float e[4] = {v.x, v.y, v.z, v.w};
    unsigned short hb[4];
    float s = 0.f;
    #pragma unroll
    for (int i = 0; i < 4; ++i) {
        _Float16 h = (_Float16)e[i];            // RNE
        float hf = (float)h;
        s = fmaf(hf, hf, s);                    // norm of the QUANTIZED vector
        hb[i] = __builtin_bit_cast(unsigned short, h);
    }
    int rr = row & 127;
    size_t base = (size_t)(row >> 7) * 16384;
    int b = (rr * 128 + c4 * 8) ^ ((rr & 7) << 4);
    uint2 hw = {(unsigned)hb[0] | ((unsigned)hb[1] << 16),
                (unsigned)hb[2] | ((unsigned)hb[3] << 16)};
    *(uint2*)((char*)H + base + b) = hw;
    s += __shfl_xor(s, 1); s += __shfl_xor(s, 2);
    s += __shfl_xor(s, 4); s += __shfl_xor(s, 8);
    if (c4 == 0) sq[row] = s;
}

// ---------------- Phase 2: 64x256 tile, 1KB-run stores via fenced LDS bounce ----------------
__global__ __launch_bounds__(256, 4) void rbf_mfma14(const unsigned short* __restrict__ H,
                                                     const float* __restrict__ sq,
                                                     float* __restrict__ out, int N) {
    __shared__ __align__(16) char smem[40960];
    unsigned short* Ah = (unsigned short*)smem;             // 8 KB  (64 rows)
    unsigned short* Bh = (unsigned short*)(smem + 8192);    // 32 KB (256 rows, 2 chunks)
    // after the post-K barrier, smem is reused as 4 x 8KB wave-private bounce buffers

    const int tid = threadIdx.x;
    const int i0 = blockIdx.y * 64, j0 = blockIdx.x * 256;
    const int w = tid >> 6, lane = tid & 63;
    const int fr = lane & 15, kg = lane >> 4;

    // ---- stage: linear 40KB copy (swizzle pre-baked; rows are contiguous 128B units,
    //      XOR only permutes bytes within a row, and i0 % 8 == 0 keeps (row&7) congruent) ----
    {
        const uint4* ga = (const uint4*)(H + (size_t)i0 * 64);
        const uint4* gb = (const uint4*)(H + (size_t)j0 * 64);
        #pragma unroll
        for (int t = 0; t < 2; ++t)
            ((uint4*)Ah)[t * 256 + tid] = ga[t * 256 + tid];
        #pragma unroll
        for (int t = 0; t < 8; ++t)
            ((uint4*)Bh)[t * 256 + tid] = gb[t * 256 + tid];
    }
    __syncthreads();

    // ---- K-loop: 2 ksteps, swapped operands -> D^T; wave rows = w*16+fr ----
    f32x4 acc[16];
    #pragma unroll
    for (int q = 0; q < 16; ++q) acc[q] = (f32x4)(0.f);

    #pragma unroll
    for (int ks = 0; ks < 2; ++ks) {
        const int kb = ks * 64 + kg * 16;
        int Ra = w * 16 + fr;                                 // 0..63
        half8 ah = *(const half8*)((const char*)Ah + ((Ra * 128 + kb) ^ ((Ra & 7) << 4)));
        #pragma unroll
        for (int q = 0; q < 16; ++q) {
            int R = q * 16 + fr;                              // 0..255
            int off = (((R & 127) * 128 + kb) ^ ((R & 7) << 4)) + ((R >> 7) << 14);
            half8 bh = *(const half8*)((const char*)Bh + off);
            acc[q] = __builtin_amdgcn_mfma_f32_16x16x32_f16(bh, ah, acc[q], 0, 0, 0);
        }
    }

    __syncthreads();   // all waves done reading Ah/Bh; smem becomes bounce space
    float* wbuf = (float*)smem + w * 2048;      // wave-private 8 KB (8 rows x 256 cols)

    const float sa = sq[i0 + w * 16 + fr];
    #pragma unroll
    for (int h = 0; h < 2; ++h) {
        // WAR fence: previous pass's cross-lane reads must not be overtaken by these writes
        asm volatile("" ::: "memory");
        __builtin_amdgcn_sched_barrier(0);
        // row-half pass: lanes with fr>>3 == h write their full 256-col row
        if ((fr >> 3) == h) {
            int rl = fr & 7;
            #pragma unroll
            for (int q = 0; q < 16; ++q) {
                int c = q * 16 + kg * 4;
                float4 sb = *(const float4*)&sq[j0 + c];
                f32x4 a = acc[q];
                f32x4 r;
                r[0] = __expf(-GAMMA * fmaxf(fmaf(-2.f, a[0], sa + sb.x), 0.f));
                r[1] = __expf(-GAMMA * fmaxf(fmaf(-2.f, a[1], sa + sb.y), 0.f));
                r[2] = __expf(-GAMMA * fmaxf(fmaf(-2.f, a[2], sa + sb.z), 0.f));
                r[3] = __expf(-GAMMA * fmaxf(fmaf(-2.f, a[3], sa + sb.w), 0.f));
                *(f32x4*)&wbuf[rl * 256 + (c ^ (rl << 2))] = r;
            }
        }
        // RAW fence: all lanes' writes complete & ordered before cross-lane readback
        asm volatile("s_waitcnt lgkmcnt(0)" ::: "memory");
        __builtin_amdgcn_sched_barrier(0);
        // readback + store: one FULL 256-col row = 1 KB contiguous per wave-instr
        #pragma unroll
        for (int rl = 0; rl < 8; ++rl) {
            f32x4 v = *(const f32x4*)&wbuf[rl * 256 + ((lane * 4) ^ (rl << 2))];
            int grow = i0 + w * 16 + h * 8 + rl;
            *(f32x4*)(out + (size_t)grow * N + j0 + lane * 4) = v;
        }
    }
}

extern "C" void kernel_launch(void* const* d_in, const int* in_sizes, int n_in,
                              void* d_out, int out_size, void* d_ws, size_t ws_size,
                              hipStream_t stream) {
    (void)n_in; (void)ws_size; (void)out_size;
    const float* x = (const float*)d_in[0];
    float* out = (float*)d_out;
    const int K = 64;
    const int N = in_sizes[0] / K;   // 8192

    unsigned short* H = (unsigned short*)d_ws;       // N*64 fp16 = 1 MB
    float* sq = (float*)(H + (size_t)N * K);         // 32 KB

    quant_kernel<<<dim3(N * K / 4 / 256), dim3(256), 0, stream>>>(x, H, sq);
    // grid: 32 x 128 = 4096 blocks, 40 KB LDS -> 4 blocks/CU
    rbf_mfma14<<<dim3(N / 256, N / 64), dim3(256), 0, stream>>>(H, sq, out, N);
}

// Round 21
// 54.366 us; speedup vs baseline: 1.2142x; 1.2142x over previous
//
#include <hip/hip_runtime.h>

// RBF Gram via single-pass fp16 MFMA with quantization-cancelling norms.
//   P1: x (fp32 [N][64]) -> H (fp16, XOR-swizzled per 128-row chunk), sq = ||fp16(x)||^2.
//   P2: 128x128 tile, 4 waves; wave w owns rows w*32..w*32+31 x all 128 cols
//       (p=0..1 row-frags, q=0..7 col-frags). After MFMA: exp -> wave-private
//       8KB LDS bounce (reusing Ah/Bh, one barrier) -> readback so each store
//       instr writes 2 FULL ROWS x 512B contiguous (vs 16 x 64B scatter).
//       Best measured: 54.1 us (R15). This is the verbatim revert.

#define GAMMA 0.5f

typedef __attribute__((ext_vector_type(8))) _Float16 half8;
typedef __attribute__((ext_vector_type(4))) float f32x4;

// ---------------- Phase 1: fp16 quantize + swizzle + quantized norms ----------------
__global__ __launch_bounds__(256) void quant_kernel(const float* __restrict__ x,
                                                    unsigned short* __restrict__ H,
                                                    float* __restrict__ sq) {
    int tid = blockIdx.x * 256 + threadIdx.x;   // one float4 (4 elems of one row)
    int row = tid >> 4, c4 = tid & 15;
    float4 v = ((const float4*)x)[tid];
    float e[4] = {v.x, v.y, v.z, v.w};
    unsigned short hb[4];
    float s = 0.f;
    #pragma unroll
    for (int i = 0; i < 4; ++i) {
        _Float16 h = (_Float16)e[i];            // RNE
        float hf = (float)h;
        s = fmaf(hf, hf, s);                    // norm of the QUANTIZED vector
        hb[i] = __builtin_bit_cast(unsigned short, h);
    }
    int rr = row & 127;
    size_t base = (size_t)(row >> 7) * 16384;
    int b = (rr * 128 + c4 * 8) ^ ((rr & 7) << 4);
    uint2 hw = {(unsigned)hb[0] | ((unsigned)hb[1] << 16),
                (unsigned)hb[2] | ((unsigned)hb[3] << 16)};
    *(uint2*)((char*)H + base + b) = hw;
    s += __shfl_xor(s, 1); s += __shfl_xor(s, 2);
    s += __shfl_xor(s, 4); s += __shfl_xor(s, 8);
    if (c4 == 0) sq[row] = s;
}

// ---------------- Phase 2: 128x128 tile, row-run stores via LDS bounce ----------------
__global__ __launch_bounds__(256, 4) void rbf_mfma10(const unsigned short* __restrict__ H,
                                                     const float* __restrict__ sq,
                                                     float* __restrict__ out, int N) {
    __shared__ __align__(16) char smem[32768];
    unsigned short* Ah = (unsigned short*)smem;             // 16 KB
    unsigned short* Bh = (unsigned short*)(smem + 16384);   // 16 KB
    // after the post-K barrier, smem is reused as 4 x 8KB wave-private bounce buffers

    const int tid = threadIdx.x;
    const int i0 = blockIdx.y * 128, j0 = blockIdx.x * 128;
    const int w = tid >> 6, lane = tid & 63;
    const int fr = lane & 15, kg = lane >> 4;
    const int wr = w * 32;                      // wave owns rows wr..wr+31, all 128 cols

    // ---- stage: linear 32KB copy (swizzle pre-baked in global layout) ----
    {
        const uint4* ga = (const uint4*)(H + (size_t)i0 * 64);
        const uint4* gb = (const uint4*)(H + (size_t)j0 * 64);
        #pragma unroll
        for (int t = 0; t < 4; ++t) {
            ((uint4*)Ah)[t * 256 + tid] = ga[t * 256 + tid];
            ((uint4*)Bh)[t * 256 + tid] = gb[t * 256 + tid];
        }
    }
    __syncthreads();

    // ---- K-loop: 2 ksteps, swapped operands -> D^T; acc[p][q] = rows x col-frags ----
    f32x4 acc[2][8];
    #pragma unroll
    for (int p = 0; p < 2; ++p)
        #pragma unroll
        for (int q = 0; q < 8; ++q) acc[p][q] = (f32x4)(0.f);

    #pragma unroll
    for (int ks = 0; ks < 2; ++ks) {
        const int kb = ks * 64 + kg * 16;
        half8 ah[2], bh[8];
        #pragma unroll
        for (int p = 0; p < 2; ++p) {
            int R = wr + p * 16 + fr;
            int off = (R * 128 + kb) ^ ((R & 7) << 4);
            ah[p] = *(const half8*)((const char*)Ah + off);
        }
        #pragma unroll
        for (int q = 0; q < 8; ++q) {
            int R = q * 16 + fr;
            int off = (R * 128 + kb) ^ ((R & 7) << 4);
            bh[q] = *(const half8*)((const char*)Bh + off);
        }
        #pragma unroll
        for (int p = 0; p < 2; ++p)
            #pragma unroll
            for (int q = 0; q < 8; ++q)
                acc[p][q] = __builtin_amdgcn_mfma_f32_16x16x32_f16(bh[q], ah[p], acc[p][q], 0, 0, 0);
    }

    __syncthreads();   // all waves done reading Ah/Bh; smem becomes bounce space
    float* wbuf = (float*)smem + w * 2048;      // wave-private 8 KB (16 rows x 128 cols)

    #pragma unroll
    for (int p = 0; p < 2; ++p) {
        // exp + swizzled ds_write: lane (fr,kg) holds rows p*16+fr, cols q*16+kg*4..+3
        float sa = sq[i0 + wr + p * 16 + fr];
        #pragma unroll
        for (int q = 0; q < 8; ++q) {
            int c = q * 16 + kg * 4;
            float4 sb = *(const float4*)&sq[j0 + c];
            f32x4 a = acc[p][q];
            float4 r;
            r.x = __expf(-GAMMA * fmaxf(fmaf(-2.f, a[0], sa + sb.x), 0.f));
            r.y = __expf(-GAMMA * fmaxf(fmaf(-2.f, a[1], sa + sb.y), 0.f));
            r.z = __expf(-GAMMA * fmaxf(fmaf(-2.f, a[2], sa + sb.z), 0.f));
            r.w = __expf(-GAMMA * fmaxf(fmaf(-2.f, a[3], sa + sb.w), 0.f));
            *(float4*)&wbuf[fr * 128 + (c ^ ((fr & 7) << 2))] = r;
        }
        // readback + store: 2 full rows x 512B contiguous per instruction
        // (same-wave RAW/WAR through wbuf ordered by compiler-inserted lgkmcnt waits)
        const int half = lane >> 5, lc = lane & 31;
        #pragma unroll
        for (int i = 0; i < 8; ++i) {
            int rl = i * 2 + half;              // row_local 0..15
            float4 v = *(const float4*)&wbuf[rl * 128 + ((lc * 4) ^ ((rl & 7) << 2))];
            int grow = i0 + wr + p * 16 + rl;
            *(float4*)(out + (size_t)grow * N + j0 + lc * 4) = v;
        }
    }
}

extern "C" void kernel_launch(void* const* d_in, const int* in_sizes, int n_in,
                              void* d_out, int out_size, void* d_ws, size_t ws_size,
                              hipStream_t stream) {
    (void)n_in; (void)ws_size; (void)out_size;
    const float* x = (const float*)d_in[0];
    float* out = (float*)d_out;
    const int K = 64;
    const int N = in_sizes[0] / K;   // 8192

    unsigned short* H = (unsigned short*)d_ws;       // N*64 fp16 = 1 MB
    float* sq = (float*)(H + (size_t)N * K);         // 32 KB

    quant_kernel<<<dim3(N * K / 4 / 256), dim3(256), 0, stream>>>(x, H, sq);
    rbf_mfma10<<<dim3(N / 128, N / 128), dim3(256), 0, stream>>>(H, sq, out, N);
}